// Round 11
// baseline (162.727 us; speedup 1.0000x reference)
//
#include <hip/hip_runtime.h>
#include <hip/hip_bf16.h>

#define N_NODES 50000
#define N_EDGES 800000
#define N_REL 8
#define N_BASES 16
#define D 128
#define NCB 196                    // coarse buckets of 256 dsts
#define NSEG (N_NODES * N_REL)     // 400000
#define NFB 1563                   // fused blocks: ceil(50000/32)
#define ACHUNK 2048

typedef __attribute__((ext_vector_type(8))) short bf16x8;
typedef __attribute__((ext_vector_type(4))) float f32x4;

__device__ inline unsigned short f2bf(float f) {
    unsigned int x = __float_as_uint(f);
    unsigned int r = x + 0x7FFFu + ((x >> 16) & 1u);
    return (unsigned short)(r >> 16);
}
__device__ inline unsigned int cvtpk(float lo, float hi) {
    unsigned int r;
    asm("v_cvt_pk_bf16_f32 %0, %1, %2" : "=v"(r) : "v"(lo), "v"(hi));
    return r;
}
__device__ inline void acc8(float* a, int4 v) {
    unsigned x;
    x = (unsigned)v.x; a[0] += __uint_as_float(x << 16); a[1] += __uint_as_float(x & 0xFFFF0000u);
    x = (unsigned)v.y; a[2] += __uint_as_float(x << 16); a[3] += __uint_as_float(x & 0xFFFF0000u);
    x = (unsigned)v.z; a[4] += __uint_as_float(x << 16); a[5] += __uint_as_float(x & 0xFFFF0000u);
    x = (unsigned)v.w; a[6] += __uint_as_float(x << 16); a[7] += __uint_as_float(x & 0xFFFF0000u);
}

// ---------------------------------------------------------------------------
// K1: fused {histA (blocks 0..781), cvtx (782..3906), makeW (3907..3978)}
#define K1_HIST 782
#define K1_CVT  3125
#define K1_MKW  72
__global__ __launch_bounds__(256) void k_setup1(const float* __restrict__ x,
                                                const float* __restrict__ coeff,
                                                const float* __restrict__ bases,
                                                const float* __restrict__ self_loop,
                                                const int* __restrict__ ei,
                                                unsigned short* __restrict__ xb,
                                                unsigned short* __restrict__ WbT,
                                                int* __restrict__ ccnt) {
    __shared__ int h[256];
    __shared__ unsigned short tile[128][17];
    const int b = blockIdx.x;
    const int t = threadIdx.x;

    if (b < K1_HIST) {
        h[t] = 0;
        __syncthreads();
        int idx = b * 1024 + t * 4;
        if (idx < N_EDGES) {
            int4 d = *(const int4*)&ei[N_EDGES + idx];
            atomicAdd(&h[d.x >> 8], 1);
            atomicAdd(&h[d.y >> 8], 1);
            atomicAdd(&h[d.z >> 8], 1);
            atomicAdd(&h[d.w >> 8], 1);
        }
        __syncthreads();
        if (t < NCB && h[t]) atomicAdd(&ccnt[t], h[t]);
    } else if (b < K1_HIST + K1_CVT) {
        int i = (b - K1_HIST) * 256 + t;
        const float4* xp = (const float4*)x;
        float4 a = xp[i * 2], bb = xp[i * 2 + 1];
        int4 o;
        o.x = (int)f2bf(a.x) | ((int)f2bf(a.y) << 16);
        o.y = (int)f2bf(a.z) | ((int)f2bf(a.w) << 16);
        o.z = (int)f2bf(bb.x) | ((int)f2bf(bb.y) << 16);
        o.w = (int)f2bf(bb.z) | ((int)f2bf(bb.w) << 16);
        ((int4*)xb)[i] = o;
    } else {
        int local = b - K1_HIST - K1_CVT;
        const int r = local >> 3, os = local & 7;
        const int i = t >> 1, ob = (t & 1) * 8;
        const int gcol = os * 16 + ob;
        float s[8];
        if (r < 8) {
            float c[16];
#pragma unroll
            for (int bb = 0; bb < 16; ++bb) c[bb] = coeff[r * 16 + bb];
#pragma unroll
            for (int j = 0; j < 8; ++j) s[j] = 0.f;
#pragma unroll
            for (int bb = 0; bb < 16; ++bb) {
                const float* bp = bases + bb * 16384 + i * 128 + gcol;
                float4 v0 = *(const float4*)bp;
                float4 v1 = *(const float4*)(bp + 4);
                s[0] += c[bb] * v0.x; s[1] += c[bb] * v0.y; s[2] += c[bb] * v0.z; s[3] += c[bb] * v0.w;
                s[4] += c[bb] * v1.x; s[5] += c[bb] * v1.y; s[6] += c[bb] * v1.z; s[7] += c[bb] * v1.w;
            }
        } else {
            const float* sp = self_loop + i * 128 + gcol;
            float4 v0 = *(const float4*)sp;
            float4 v1 = *(const float4*)(sp + 4);
            s[0] = v0.x; s[1] = v0.y; s[2] = v0.z; s[3] = v0.w;
            s[4] = v1.x; s[5] = v1.y; s[6] = v1.z; s[7] = v1.w;
        }
#pragma unroll
        for (int j = 0; j < 8; ++j) tile[i][ob + j] = f2bf(s[j]);
        __syncthreads();
        const int o = t >> 4, ic = (t & 15) << 3;
        unsigned int pk[4];
#pragma unroll
        for (int j = 0; j < 4; ++j)
            pk[j] = (unsigned int)tile[ic + j * 2][o] | ((unsigned int)tile[ic + j * 2 + 1][o] << 16);
        *(int4*)&WbT[(size_t)r * 16384 + (os * 16 + o) * 128 + ic] = *(int4*)pk;
    }
}

// ---------------------------------------------------------------------------
// exclusive scan of ccnt[196] -> coff[197], gcur; pad roff2 tail with total
__global__ __launch_bounds__(256) void k_scanA1(const int* __restrict__ ccnt,
                                                int* __restrict__ coff,
                                                int* __restrict__ gcur,
                                                int* __restrict__ roff2) {
    int t = threadIdx.x;
    int v = (t < NCB) ? ccnt[t] : 0;
    int lane = t & 63, wv = t >> 6;
    int inc = v;
#pragma unroll
    for (int off = 1; off < 64; off <<= 1) {
        int y = __shfl_up(inc, off);
        if (lane >= off) inc += y;
    }
    __shared__ int ws4[4];
    __shared__ int tot;
    if (lane == 63) ws4[wv] = inc;
    __syncthreads();
    int wb = 0;
    for (int i = 0; i < wv; ++i) wb += ws4[i];
    int ex = wb + inc - v;
    if (t < NCB) { coff[t] = ex; gcur[t] = ex; }
    if (t == NCB - 1) { coff[NCB] = ex + v; tot = ex + v; }
    __syncthreads();
    // pad: segments for dst in [50000, 50016) must read empty
    for (int i = t; i < 192; i += 256) roff2[NSEG + i] = tot;
}

// ---------------------------------------------------------------------------
// bucket edges into coarse segments; rec = src | rel<<16 | (dst&255)<<19
__global__ __launch_bounds__(256) void k_bucketA(const int* __restrict__ ei,
                                                 const int* __restrict__ et,
                                                 int* __restrict__ gcur,
                                                 unsigned int* __restrict__ recA) {
    __shared__ int lcnt[NCB], lbase[NCB];
    const int base = blockIdx.x * ACHUNK;
    const int t = threadIdx.x;
    if (t < NCB) lcnt[t] = 0;
    __syncthreads();
    unsigned int rec[8];
    int mb[8];
#pragma unroll
    for (int i = 0; i < 8; ++i) {
        int e = base + t + i * 256;
        if (e < N_EDGES) {
            int src = ei[e];
            int dst = ei[N_EDGES + e];
            int r = et[e];
            rec[i] = (unsigned)src | ((unsigned)r << 16) | ((unsigned)(dst & 255) << 19);
            mb[i] = dst >> 8;
            atomicAdd(&lcnt[mb[i]], 1);
        } else mb[i] = -1;
    }
    __syncthreads();
    if (t < NCB) lbase[t] = lcnt[t] ? atomicAdd(&gcur[t], lcnt[t]) : 0;
    __syncthreads();
    if (t < NCB) lcnt[t] = 0;
    __syncthreads();
#pragma unroll
    for (int i = 0; i < 8; ++i) {
        if (mb[i] < 0) continue;
        int pos = lbase[mb[i]] + atomicAdd(&lcnt[mb[i]], 1);
        recA[pos] = rec[i];
    }
}

// ---------------------------------------------------------------------------
// per coarse bucket: (dst,rel)-sorted csr16 + roff2 (all LDS atomics)
__global__ __launch_bounds__(256) void k_buildC(const unsigned int* __restrict__ recA,
                                                const int* __restrict__ coff,
                                                int* __restrict__ roff2,
                                                unsigned short* __restrict__ csr16) {
    const int b = blockIdx.x, t = threadIdx.x;
    const int s0 = coff[b], s1 = coff[b + 1];
    __shared__ int h2[2048];    // (dst&255)*8 + rel
    __shared__ int cur2[2048];
    __shared__ int ws4[4];
    for (int i = t; i < 2048; i += 256) h2[i] = 0;
    __syncthreads();
    for (int i = s0 + t; i < s1; i += 256) {
        unsigned int p = recA[i];
        atomicAdd(&h2[((p >> 19) & 255) * 8 + ((p >> 16) & 7)], 1);
    }
    __syncthreads();
    int pre[8], sum = 0;
#pragma unroll
    for (int j = 0; j < 8; ++j) { pre[j] = sum; sum += h2[t * 8 + j]; }
    int lane = t & 63, wv = t >> 6;
    int inc = sum;
#pragma unroll
    for (int off = 1; off < 64; off <<= 1) {
        int y = __shfl_up(inc, off);
        if (lane >= off) inc += y;
    }
    if (lane == 63) ws4[wv] = inc;
    __syncthreads();
    int wb = 0;
    for (int i = 0; i < wv; ++i) wb += ws4[i];
    int ex = wb + inc - sum;
    int dst = (b << 8) + t;
#pragma unroll
    for (int j = 0; j < 8; ++j) cur2[t * 8 + j] = ex + pre[j];
    if (dst < N_NODES) {
#pragma unroll
        for (int j = 0; j < 8; ++j) roff2[dst * 8 + j] = s0 + ex + pre[j];
    }
    __syncthreads();
    for (int i = s0 + t; i < s1; i += 256) {
        unsigned int p = recA[i];
        int idx2 = ((p >> 19) & 255) * 8 + ((p >> 16) & 7);
        int pos = s0 + atomicAdd(&cur2[idx2], 1);
        csr16[pos] = (unsigned short)(p & 0xFFFF);
    }
}

// ---------------------------------------------------------------------------
// FUSED v3: 32 dsts/block, 8 waves. Phase 1: register aggregation, lane =
// (rel, dim-slot): lane owns 16 dims of one rel, acc in 16 regs; wave = 4
// dsts (contiguous csr range, LDS-staged). Pack bf16 (dinv-scaled) into
// 64 KB XOR-swizzled agg LDS. Phase 2: 9-panel MFMA (K=1152) -> fp32 out.
__global__ __launch_bounds__(512) void k_fused3(const unsigned short* __restrict__ xb,
                                                const unsigned short* __restrict__ WbT,
                                                const unsigned short* __restrict__ csr16,
                                                const int* __restrict__ roff2,
                                                float* __restrict__ out) {
    __shared__ __attribute__((aligned(16))) unsigned short agg[32 * 1024];  // 64 KB
    __shared__ int roff_s[257];
    __shared__ unsigned short sE[8][128];
    const int g = blockIdx.x, g32 = g * 32, t = threadIdx.x;
    const int wv = t >> 6, lane = t & 63;

    if (t < 257) roff_s[t] = roff2[g * 256 + t];
    __syncthreads();

    // ---- phase 1
    {
        const int r = lane >> 3, slot = lane & 7;       // rel group, 16-dim slot
        const int e0 = roff_s[wv * 32];
        const int nE = roff_s[wv * 32 + 32] - e0;
        for (int i = lane; i < nE && i < 128; i += 64) sE[wv][i] = csr16[e0 + i];
    }
    __syncthreads();   // sE visible across lanes
    {
        const int r = lane >> 3, slot = lane & 7;
        const int e0 = roff_s[wv * 32];
        const int nE = roff_s[wv * 32 + 32] - e0;
        const bool fast = (nE <= 128);
        const int so = slot * 16;
#pragma unroll 1
        for (int dd = 0; dd < 4; ++dd) {
            const int dl = wv * 4 + dd;
            const int a0 = roff_s[dl * 8 + r] - e0;
            const int a1 = roff_s[dl * 8 + r + 1] - e0;
            float acc[16];
#pragma unroll
            for (int q = 0; q < 16; ++q) acc[q] = 0.f;
            int j = a0;
            if (fast) {
                for (; j + 1 < a1; j += 2) {
                    int s0 = sE[wv][j], s1 = sE[wv][j + 1];
                    const unsigned short* p0 = &xb[s0 * 128 + so];
                    const unsigned short* p1 = &xb[s1 * 128 + so];
                    int4 u0 = *(const int4*)p0;
                    int4 u1 = *(const int4*)(p0 + 8);
                    int4 w0 = *(const int4*)p1;
                    int4 w1 = *(const int4*)(p1 + 8);
                    acc8(acc, u0); acc8(acc + 8, u1);
                    acc8(acc, w0); acc8(acc + 8, w1);
                }
                if (j < a1) {
                    int s0 = sE[wv][j];
                    const unsigned short* p0 = &xb[s0 * 128 + so];
                    int4 u0 = *(const int4*)p0;
                    int4 u1 = *(const int4*)(p0 + 8);
                    acc8(acc, u0); acc8(acc + 8, u1);
                }
            } else {
                for (; j + 1 < a1; j += 2) {
                    int s0 = csr16[e0 + j], s1 = csr16[e0 + j + 1];
                    const unsigned short* p0 = &xb[s0 * 128 + so];
                    const unsigned short* p1 = &xb[s1 * 128 + so];
                    int4 u0 = *(const int4*)p0;
                    int4 u1 = *(const int4*)(p0 + 8);
                    int4 w0 = *(const int4*)p1;
                    int4 w1 = *(const int4*)(p1 + 8);
                    acc8(acc, u0); acc8(acc + 8, u1);
                    acc8(acc, w0); acc8(acc + 8, w1);
                }
                if (j < a1) {
                    int s0 = csr16[e0 + j];
                    const unsigned short* p0 = &xb[s0 * 128 + so];
                    int4 u0 = *(const int4*)p0;
                    int4 u1 = *(const int4*)(p0 + 8);
                    acc8(acc, u0); acc8(acc + 8, u1);
                }
            }
            float dinv = 1.0f / fmaxf((float)(a1 - a0), 1.0f);
            unsigned pk[8];
#pragma unroll
            for (int q = 0; q < 8; ++q) pk[q] = cvtpk(acc[2 * q] * dinv, acc[2 * q + 1] * dinv);
            const int mask = (dl & 7) << 4;
            const int o1 = (r * 256 + slot * 32) ^ mask;     // 16B-aligned
            char* rowp = (char*)agg + dl * 2048;
            *(int4*)(rowp + o1) = make_int4((int)pk[0], (int)pk[1], (int)pk[2], (int)pk[3]);
            *(int4*)(rowp + (o1 ^ 16)) = make_int4((int)pk[4], (int)pk[5], (int)pk[6], (int)pk[7]);
        }
    }
    __syncthreads();

    // ---- phase 2: wave wv -> cols [wv*16, wv*16+16), rows 0..31 (2 tiles)
    const int lr = lane & 15, lg = lane >> 4;
    const int colb = wv << 4;
    const int mask = (lr & 7) << 4;                  // same for rows lr and lr+16
    f32x4 acc0 = {0.f, 0.f, 0.f, 0.f}, acc1 = {0.f, 0.f, 0.f, 0.f};
#pragma unroll
    for (int rel = 0; rel < 8; ++rel) {
        const unsigned short* Wp = WbT + rel * 16384 + (colb + lr) * 128;
        const char* rA = (const char*)agg + lr * 2048;
        const char* rB = (const char*)agg + (lr + 16) * 2048;
#pragma unroll
        for (int kk = 0; kk < 4; ++kk) {
            bf16x8 bfr = *(const bf16x8*)&Wp[kk * 32 + lg * 8];
            int kb = (rel * 256 + kk * 64 + lg * 16) ^ mask;
            bf16x8 a0 = *(const bf16x8*)(rA + kb);
            bf16x8 a1 = *(const bf16x8*)(rB + kb);
            acc0 = __builtin_amdgcn_mfma_f32_16x16x32_bf16(a0, bfr, acc0, 0, 0, 0);
            acc1 = __builtin_amdgcn_mfma_f32_16x16x32_bf16(a1, bfr, acc1, 0, 0, 0);
        }
    }
    {   // self-loop panel: A rows straight from xb
        const unsigned short* Wp = WbT + 8 * 16384 + (colb + lr) * 128;
        int r0 = min(g32 + lr, N_NODES - 1);
        int r1 = min(g32 + 16 + lr, N_NODES - 1);
#pragma unroll
        for (int kk = 0; kk < 4; ++kk) {
            bf16x8 bfr = *(const bf16x8*)&Wp[kk * 32 + lg * 8];
            bf16x8 a0 = *(const bf16x8*)&xb[(size_t)r0 * 128 + kk * 32 + lg * 8];
            bf16x8 a1 = *(const bf16x8*)&xb[(size_t)r1 * 128 + kk * 32 + lg * 8];
            acc0 = __builtin_amdgcn_mfma_f32_16x16x32_bf16(a0, bfr, acc0, 0, 0, 0);
            acc1 = __builtin_amdgcn_mfma_f32_16x16x32_bf16(a1, bfr, acc1, 0, 0, 0);
        }
    }
#pragma unroll
    for (int q = 0; q < 4; ++q) {
        int row = g32 + lg * 4 + q;
        if (row < N_NODES) out[(size_t)row * 128 + colb + lr] = acc0[q];
    }
#pragma unroll
    for (int q = 0; q < 4; ++q) {
        int row = g32 + 16 + lg * 4 + q;
        if (row < N_NODES) out[(size_t)row * 128 + colb + lr] = acc1[q];
    }
}

// ---------------------------------------------------------------------------
extern "C" void kernel_launch(void* const* d_in, const int* in_sizes, int n_in,
                              void* d_out, int out_size, void* d_ws, size_t ws_size,
                              hipStream_t stream) {
    const float* x         = (const float*)d_in[0];
    const float* bases     = (const float*)d_in[1];
    const float* coeff     = (const float*)d_in[2];
    const float* self_loop = (const float*)d_in[3];
    const int*   ei        = (const int*)d_in[4];
    const int*   et        = (const int*)d_in[5];
    float* out = (float*)d_out;

    char* ws = (char*)d_ws;
    size_t o = 0;
    auto alloc = [&](size_t bytes) { size_t r = o; o += (bytes + 255) & ~(size_t)255; return r; };
    size_t o_ccnt   = alloc(256 * 4);                        // zeroed
    size_t zero_end = o;
    size_t o_coff   = alloc((NCB + 1) * 4);
    size_t o_gcur   = alloc(NCB * 4);
    size_t o_recA   = alloc((size_t)N_EDGES * 4);
    size_t o_csr16  = alloc((size_t)N_EDGES * 2);
    size_t o_roff2  = alloc((size_t)(NSEG + 192) * 4);
    size_t o_WbT    = alloc((size_t)9 * 16384 * 2);
    size_t o_xb     = alloc((size_t)N_NODES * D * 2 + 4096);
    if (ws_size < o) return;

    int*            ccnt  = (int*)(ws + o_ccnt);
    int*            coff  = (int*)(ws + o_coff);
    int*            gcur  = (int*)(ws + o_gcur);
    unsigned int*   recA  = (unsigned int*)(ws + o_recA);
    unsigned short* csr16 = (unsigned short*)(ws + o_csr16);
    int*            roff2 = (int*)(ws + o_roff2);
    unsigned short* WbT   = (unsigned short*)(ws + o_WbT);
    unsigned short* xb    = (unsigned short*)(ws + o_xb);

    hipMemsetAsync(ccnt, 0, zero_end, stream);

    k_setup1<<<K1_HIST + K1_CVT + K1_MKW, 256, 0, stream>>>(x, coeff, bases, self_loop,
                                                            ei, xb, WbT, ccnt);
    k_scanA1<<<1, 256, 0, stream>>>(ccnt, coff, gcur, roff2);
    k_bucketA<<<(N_EDGES + ACHUNK - 1) / ACHUNK, 256, 0, stream>>>(ei, et, gcur, recA);
    k_buildC<<<NCB, 256, 0, stream>>>(recA, coff, roff2, csr16);
    k_fused3<<<NFB, 512, 0, stream>>>(xb, WbT, csr16, roff2, out);
}